// Round 5
// baseline (188.458 us; speedup 1.0000x reference)
//
#include <hip/hip_runtime.h>

#define BB 8
#define TT 256
#define UU 64
#define VV 512
#define U1 (UU + 1)
#define NPROD 512
#define SLOT 66

#define LOG2E 1.4426950408889634f
#define LN2   0.6931471805599453f
#define NEG_INF (-__builtin_inff())

typedef float floatx4 __attribute__((ext_vector_type(4)));

__device__ __forceinline__ float vexp2(float x) {
    float r; asm("v_exp_f32 %0, %1" : "=v"(r) : "v"(x)); return r;
}
__device__ __forceinline__ float vlog2(float x) {
    float r; asm("v_log_f32 %0, %1" : "=v"(r) : "v"(x)); return r;
}

template<int CTRL, int RMASK>
__device__ __forceinline__ float dpp_mov(float v, float oldv) {
    int r = __builtin_amdgcn_update_dpp(__float_as_int(oldv), __float_as_int(v),
                                        CTRL, RMASK, 0xf, false);
    return __int_as_float(r);
}

// wave64 inclusive add-scan via DPP (identity = 0)
__device__ __forceinline__ float wave_addscan(float v) {
    v += dpp_mov<0x111, 0xf>(v, 0.f);
    v += dpp_mov<0x112, 0xf>(v, 0.f);
    v += dpp_mov<0x114, 0xf>(v, 0.f);
    v += dpp_mov<0x118, 0xf>(v, 0.f);
    v += dpp_mov<0x142, 0xa>(v, 0.f);
    v += dpp_mov<0x143, 0xc>(v, 0.f);
    return v;
}

#define ALOADF(ptr) __hip_atomic_load((ptr), __ATOMIC_RELAXED, __HIP_MEMORY_SCOPE_AGENT)
#define ASTORF(ptr, v) __hip_atomic_store((ptr), (v), __ATOMIC_RELAXED, __HIP_MEMORY_SCOPE_AGENT)

// Kernel 0: reset flags + output (replay-safe; runs before the fused kernel).
__global__ __launch_bounds__(256) void k_zero(int* __restrict__ flags, float* __restrict__ out) {
    int i = blockIdx.x * 256 + threadIdx.x;
    if (i < BB * TT) __hip_atomic_store(&flags[i], 0, __ATOMIC_RELAXED, __HIP_MEMORY_SCOPE_AGENT);
    if (i == 0) out[0] = 0.f;
}

// Fused producer/consumer kernel.
// Blocks 0..7: consumers (one wave each, batch b = blockIdx).
// Blocks 8..8+NPROD-1: producers; block p=blockIdx-8 handles b=p&7, t=p/8+{0,64,128,192}
// (t-major rounds so the publish frontier advances in t-order).
// Per (b,t) slot, producer publishes cumx[0..64] (CX) and P=blank+cumx (PP), then a
// release flag. Consumer computes D_s[u] = P_s[u]-CX_{s+1}[u] on the fly.
__global__ __launch_bounds__(256) void k_fused(const float* __restrict__ logits,
                                               const int* __restrict__ targets,
                                               const int* __restrict__ loglen,
                                               const int* __restrict__ tgtlen,
                                               float* __restrict__ PP,
                                               float* __restrict__ CX,
                                               int* __restrict__ flags,
                                               float* __restrict__ out) {
    if (blockIdx.x >= 8) {
        // ---------------- producer ----------------
        int p = blockIdx.x - 8;
        int b = p & 7;
        int tbase = p >> 3;
        int w = threadIdx.x >> 6;
        int lane = threadIdx.x & 63;
        __shared__ float blankS[U1];
        __shared__ float emitS[UU];

        for (int k = 0; k < 4; ++k) {
            int t = tbase + 64 * k;
            const float* base = logits + (size_t)(b * TT + t) * U1 * VV;
            floatx4 v0, v1;
            {
                const float* row = base + (size_t)w * VV;
                v0 = *(const floatx4*)(row + lane * 4);
                v1 = *(const floatx4*)(row + 256 + lane * 4);
            }
            for (int r = w; r < U1; r += 4) {
                floatx4 n0 = {0.f, 0.f, 0.f, 0.f}, n1 = {0.f, 0.f, 0.f, 0.f};
                if (r + 4 < U1) {
                    const float* row = base + (size_t)(r + 4) * VV;
                    n0 = *(const floatx4*)(row + lane * 4);
                    n1 = *(const floatx4*)(row + 256 + lane * 4);
                }
                float m = fmaxf(fmaxf(fmaxf(v0.x, v0.y), fmaxf(v0.z, v0.w)),
                                fmaxf(fmaxf(v1.x, v1.y), fmaxf(v1.z, v1.w)));
                #pragma unroll
                for (int off = 32; off; off >>= 1) m = fmaxf(m, __shfl_xor(m, off));
                float s = __expf(v0.x - m) + __expf(v0.y - m) + __expf(v0.z - m) + __expf(v0.w - m)
                        + __expf(v1.x - m) + __expf(v1.y - m) + __expf(v1.z - m) + __expf(v1.w - m);
                #pragma unroll
                for (int off = 32; off; off >>= 1) s += __shfl_xor(s, off);
                float lse = m + __logf(s);

                if (lane == 0) blankS[r] = v0.x - lse;
                if (r < UU) {
                    int tgt = targets[b * UU + r];          // in [1, V)
                    int owner = (tgt & 255) >> 2;
                    if (lane == owner) {
                        int slot = tgt & 3;
                        float x0 = (tgt < 256) ? v0.x : v1.x;
                        float x1 = (tgt < 256) ? v0.y : v1.y;
                        float x2 = (tgt < 256) ? v0.z : v1.z;
                        float x3 = (tgt < 256) ? v0.w : v1.w;
                        float val = (slot == 0) ? x0 : (slot == 1) ? x1 : (slot == 2) ? x2 : x3;
                        emitS[r] = val - lse;
                    }
                }
                v0 = n0; v1 = n1;
            }
            __syncthreads();
            if (w == 0) {
                float e = emitS[lane];
                float incl = wave_addscan(e);
                float excl = incl - e;                       // exact 0 at lane 0
                float tot = __shfl(incl, 63);
                float bl64 = blankS[64];
                size_t slot = (size_t)(b * TT + t) * SLOT;
                ASTORF(&CX[slot + lane], excl);
                ASTORF(&PP[slot + lane], blankS[lane] + excl);
                if (lane == 0) {
                    ASTORF(&CX[slot + 64], tot);
                    ASTORF(&PP[slot + 64], bl64 + tot);
                    __hip_atomic_store(&flags[b * TT + t], 1,
                                       __ATOMIC_RELEASE, __HIP_MEMORY_SCOPE_AGENT);
                }
            }
            __syncthreads();   // protect LDS reuse across rounds
        }
        return;
    }

    // ---------------- consumer ----------------
    if (threadIdx.x >= 64) return;
    int b = blockIdx.x;
    int l = threadIdx.x;                   // owns u = l; u=64 side-chain lives in lane 63
    int t_idx = loglen[b] - 1;
    int u_idx = tgtlen[b];
    int t_sel = t_idx - 1;
    const float* Pb = PP + (size_t)b * TT * SLOT;
    const float* Cb = CX + (size_t)b * TT * SLOT;
    const int* fb = flags + b * TT;

    int F = 0;                             // flags [0,F) confirmed set

#define ENSURE(need_) do { int nn = (need_);                                        \
        while (F <= nn) {                                                           \
            while (__hip_atomic_load(&fb[F], __ATOMIC_ACQUIRE,                      \
                                     __HIP_MEMORY_SCOPE_AGENT) == 0)                \
                __builtin_amdgcn_s_sleep(2);                                        \
            ++F;                                                                    \
        } } while (0)

    float am = 0.f, as = 1.f, a64m = 0.f, a64s = 1.f, gm = 0.f, gs = 1.f;
    float pA[4], cA[4], pB[4], cB[4], pC[4], cC[4];
    float p64A[4] = {0,0,0,0}, c64A[4] = {0,0,0,0};
    float p64B[4] = {0,0,0,0}, c64B[4] = {0,0,0,0};
    float p64C[4] = {0,0,0,0}, c64C[4] = {0,0,0,0};

#define LOADC(p_, c_, p64_, c64_, cc_) do { int c__ = (cc_);                        \
        if (c__ < 64) {                                                             \
            ENSURE(4 * c__ + 4 < 255 ? 4 * c__ + 4 : 255);                          \
            _Pragma("unroll")                                                       \
            for (int i = 0; i < 4; ++i) { int s = 4 * c__ + i;                      \
                if (s < 255) {                                                      \
                    p_[i] = ALOADF(Pb + (size_t)s * SLOT + l);                      \
                    c_[i] = ALOADF(Cb + (size_t)(s + 1) * SLOT + l);                \
                    if (l == 63) {                                                  \
                        p64_[i] = ALOADF(Pb + (size_t)s * SLOT + 64);               \
                        c64_[i] = ALOADF(Cb + (size_t)(s + 1) * SLOT + 64);         \
                    }                                                               \
                } } } } while (0)

#define SCAN_STAGE(CTRL, RM)                                    \
    {   float pm = dpp_mov<CTRL, RM>(fm, NEG_INF);              \
        float ps = dpp_mov<CTRL, RM>(fs, 0.f);                  \
        float M  = fmaxf(fm, pm);                               \
        float ea = vexp2(fm - M);                               \
        float eb = vexp2(pm - M);                               \
        fs = fs * ea + ps * eb;                                 \
        fm = M; }

#define STEP4(p_, c_, p64_, c64_, cc_) do { int cbase = 4 * (cc_);                  \
        _Pragma("unroll")                                                           \
        for (int i = 0; i < 4; ++i) {                                               \
            int s = cbase + i;                                                      \
            if (s >= 255) break;                                                    \
            float fm = fmaf(p_[i] - c_[i], LOG2E, am);                              \
            float fs = as;                                                          \
            SCAN_STAGE(0x111, 0xf)                                                  \
            SCAN_STAGE(0x112, 0xf)                                                  \
            SCAN_STAGE(0x114, 0xf)                                                  \
            SCAN_STAGE(0x118, 0xf)                                                  \
            SCAN_STAGE(0x142, 0xa)                                                  \
            SCAN_STAGE(0x143, 0xc)                                                  \
            float f64m = fmaf(p64_[i] - c64_[i], LOG2E, a64m);                      \
            float f64s = a64s;                                                      \
            {   float M  = fmaxf(f64m, fm);                                         \
                float ea = vexp2(f64m - M);                                         \
                float eb = vexp2(fm - M);                                           \
                f64s = f64s * ea + fs * eb;                                         \
                f64m = M; }                                                         \
            if (s == t_sel) {                                                       \
                if (l == u_idx) { gm = fm; gs = fs; }                               \
                if (u_idx == 64 && l == 63) { gm = f64m; gs = f64s; }               \
            }                                                                       \
            am = fm; as = fs; a64m = f64m; a64s = f64s;                             \
        }                                                                           \
        { int e1; as = frexpf(as, &e1); am += (float)e1;                            \
          int e2; a64s = frexpf(a64s, &e2); a64m += (float)e2; }                    \
    } while (0)

    LOADC(pA, cA, p64A, c64A, 0);
    LOADC(pB, cB, p64B, c64B, 1);
    LOADC(pC, cC, p64C, c64C, 2);

    for (int cc = 0; cc < 21; ++cc) {
        STEP4(pA, cA, p64A, c64A, 3 * cc + 0);  LOADC(pA, cA, p64A, c64A, 3 * cc + 3);
        STEP4(pB, cB, p64B, c64B, 3 * cc + 1);  LOADC(pB, cB, p64B, c64B, 3 * cc + 4);
        STEP4(pC, cC, p64C, c64C, 3 * cc + 2);  LOADC(pC, cC, p64C, c64C, 3 * cc + 5);
    }
    STEP4(pA, cA, p64A, c64A, 63);

    int wl = (u_idx < 64) ? u_idx : 63;
    if (l == wl) {
        float g = (gm + vlog2(gs)) * LN2;
        float Pfin = ALOADF(Pb + (size_t)t_idx * SLOT + u_idx);
        atomicAdd(out, -0.125f * (Pfin + g));
    }
#undef ENSURE
#undef LOADC
#undef SCAN_STAGE
#undef STEP4
}

extern "C" void kernel_launch(void* const* d_in, const int* in_sizes, int n_in,
                              void* d_out, int out_size, void* d_ws, size_t ws_size,
                              hipStream_t stream) {
    const float* logits  = (const float*)d_in[0];
    const int*   targets = (const int*)d_in[1];
    const int*   loglen  = (const int*)d_in[2];
    const int*   tgtlen  = (const int*)d_in[3];

    float* ws    = (float*)d_ws;
    float* PP    = ws;                        // 8*256*66 = 135168
    float* CX    = PP + BB * TT * SLOT;       // 135168
    int*   flags = (int*)(CX + BB * TT * SLOT); // 2048 ints

    k_zero<<<8, 256, 0, stream>>>(flags, (float*)d_out);
    k_fused<<<8 + NPROD, 256, 0, stream>>>(logits, targets, loglen, tgtlen,
                                           PP, CX, flags, (float*)d_out);
}

// Round 7
// 85.399 us; speedup vs baseline: 2.2068x; 2.2068x over previous
//
#include <hip/hip_runtime.h>

#define BB 8
#define TT 256
#define UU 64
#define VV 512
#define U1 (UU + 1)

#define LOG2E 1.4426950408889634f
#define LN2   0.6931471805599453f
#define NEG_INF (-__builtin_inff())

typedef float floatx4 __attribute__((ext_vector_type(4)));

__device__ __forceinline__ float vexp2(float x) {
    float r; asm("v_exp_f32 %0, %1" : "=v"(r) : "v"(x)); return r;
}
__device__ __forceinline__ float vlog2(float x) {
    float r; asm("v_log_f32 %0, %1" : "=v"(r) : "v"(x)); return r;
}

template<int CTRL, int RMASK>
__device__ __forceinline__ float dpp_mov(float v, float oldv) {
    int r = __builtin_amdgcn_update_dpp(__float_as_int(oldv), __float_as_int(v),
                                        CTRL, RMASK, 0xf, false);
    return __int_as_float(r);
}

// wave64 inclusive add-scan via DPP (identity = 0); strictly low-lane -> high-lane.
__device__ __forceinline__ float wave_addscan(float v) {
    v += dpp_mov<0x111, 0xf>(v, 0.f);
    v += dpp_mov<0x112, 0xf>(v, 0.f);
    v += dpp_mov<0x114, 0xf>(v, 0.f);
    v += dpp_mov<0x118, 0xf>(v, 0.f);
    v += dpp_mov<0x142, 0xa>(v, 0.f);
    v += dpp_mov<0x143, 0xc>(v, 0.f);
    return v;
}

// Kernel 1: per-row log-softmax; extract blank lp and target (emit) lp.
// CULLED: rows with t >= loglen[b] or u > tgtlen[b] are dead (scan is a strict
// low->high prefix; poison in dead lanes/rows never reaches live ones).
__global__ __launch_bounds__(256) void k_logsm(const float* __restrict__ logits,
                                               const int* __restrict__ targets,
                                               const int* __restrict__ loglen,
                                               const int* __restrict__ tgtlen,
                                               float* __restrict__ blank,
                                               float* __restrict__ emit) {
    int wave = (int)((blockIdx.x * blockDim.x + threadIdx.x) >> 6);
    int lane = threadIdx.x & 63;
    const int nrows = BB * TT * U1;
    if (wave >= nrows) return;
    int u  = wave % U1;
    int bt = wave / U1;
    int b  = bt / TT;
    int t  = bt - b * TT;
    if (t >= loglen[b] || u > tgtlen[b]) return;   // dead row

    const float* row = logits + (size_t)wave * VV;
    floatx4 v0 = __builtin_nontemporal_load((const floatx4*)(row + lane * 4));
    floatx4 v1 = __builtin_nontemporal_load((const floatx4*)(row + 256 + lane * 4));
    float m = fmaxf(fmaxf(fmaxf(v0.x, v0.y), fmaxf(v0.z, v0.w)),
                    fmaxf(fmaxf(v1.x, v1.y), fmaxf(v1.z, v1.w)));
    #pragma unroll
    for (int off = 32; off; off >>= 1) m = fmaxf(m, __shfl_xor(m, off));
    float s = __expf(v0.x - m) + __expf(v0.y - m) + __expf(v0.z - m) + __expf(v0.w - m)
            + __expf(v1.x - m) + __expf(v1.y - m) + __expf(v1.z - m) + __expf(v1.w - m);
    #pragma unroll
    for (int off = 32; off; off >>= 1) s += __shfl_xor(s, off);
    float lse = m + __logf(s);

    if (lane == 0) blank[wave] = v0.x - lse;
    if (u < UU) {
        int tgt = targets[b * UU + u];           // in [1, V)
        int owner = (tgt & 255) >> 2;
        if (lane == owner) {
            int slot = tgt & 3;
            float x0 = (tgt < 256) ? v0.x : v1.x;
            float x1 = (tgt < 256) ? v0.y : v1.y;
            float x2 = (tgt < 256) ? v0.z : v1.z;
            float x3 = (tgt < 256) ? v0.w : v1.w;
            float val = (slot == 0) ? x0 : (slot == 1) ? x1 : (slot == 2) ? x2 : x3;
            emit[bt * UU + u] = val - lse;
        }
    }
}

// Kernel 2: build cum (exclusive, nat log) and D/z64 (log2 domain) for the scan.
// Culled: waves with t >= loglen[b] produce nothing the scan reads.
__global__ __launch_bounds__(256) void k_prep(const float* __restrict__ emit,
                                              const float* __restrict__ blank,
                                              const int* __restrict__ loglen,
                                              float* __restrict__ cum,
                                              float* __restrict__ Dg,
                                              float* __restrict__ z64,
                                              float* __restrict__ out0) {
    int wave = (int)((blockIdx.x * blockDim.x + threadIdx.x) >> 6);
    int l = threadIdx.x & 63;
    if (wave >= BB * TT) return;
    if (wave == 0 && l == 0) out0[0] = 0.f;   // zero output for k_scan's atomicAdd
    int b = wave >> 8, t = wave & 255;
    if (t >= loglen[b]) return;               // scan never reads cum/D/z64 past t_idx
    float e = emit[wave * UU + l];
    float incl = wave_addscan(e);
    float excl = incl - e;                    // exact 0 at lane 0
    cum[wave * U1 + l] = excl;
    float inclT63 = __shfl(incl, 63);
    if (l == 63) cum[wave * U1 + 64] = incl;
    if (t >= 1) {
        float eP = emit[(wave - 1) * UU + l];
        float inclP = wave_addscan(eP);
        float exclP = inclP - eP;
        float bl = blank[(size_t)(wave - 1) * U1 + l];
        int s = t - 1;
        Dg[((b * 64 + (s >> 2)) * 64 + l) * 4 + (s & 3)] = (bl + exclP - excl) * LOG2E;
        float inclP63 = __shfl(inclP, 63);
        if (l == 0)
            z64[wave - 1] = (blank[(size_t)(wave - 1) * U1 + 64] + inclP63 - inclT63) * LOG2E;
    }
}

// Kernel 3: per-batch alpha recursion. State carried as (m,s) pairs: value = m + log2(s).
// Runs only t_lim = loglen[b]-1 steps (mean ~192, not 255).
__global__ __launch_bounds__(64) void k_scan(const float* __restrict__ Dg,
                                             const float* __restrict__ z64,
                                             const float* __restrict__ cum,
                                             const float* __restrict__ blank,
                                             const int* __restrict__ loglen,
                                             const int* __restrict__ tgtlen,
                                             float* __restrict__ out) {
    int b = blockIdx.x;
    int l = threadIdx.x;                  // owns u = l (0..63); u=64 side-chain in lane 63
    int t_idx = loglen[b] - 1;
    int u_idx = tgtlen[b];
    int t_sel = t_idx - 1;
    int t_lim = t_idx;                    // execute steps s = 0 .. t_lim-1 (last = t_sel)
    const float* Db = Dg + (size_t)b * 64 * 64 * 4;
    const float* zb = z64 + b * 256;

    float am = 0.f, as = 1.f;             // g pair, g = am + log2(as); init g=0
    float a64m = 0.f, a64s = 1.f;         // u=64 pair
    float gm = 0.f, gs = 1.f;             // recorded pair

    float rA[4], zA[4], rB[4], zB[4], rC[4], zC[4];

#define LOADG(r_, z_, c_) do { int c__ = (c_);                                   \
        if (c__ < 64 && 4 * c__ < t_lim) {                                       \
            *(float4*)(r_) = *(const float4*)(Db + (c__ * 64 + l) * 4);          \
            *(float4*)(z_) = *(const float4*)(zb + 4 * c__);                     \
        } } while (0)

#define SCAN_STAGE(CTRL, RM)                                    \
    {   float pm = dpp_mov<CTRL, RM>(fm, NEG_INF);              \
        float ps = dpp_mov<CTRL, RM>(fs, 0.f);                  \
        float M  = fmaxf(fm, pm);                               \
        float ea = vexp2(fm - M);                               \
        float eb = vexp2(pm - M);                               \
        fs = fs * ea + ps * eb;                                 \
        fm = M; }

#define STEP4(r_, z_, c_) do { int cbase = 4 * (c_);                             \
        _Pragma("unroll")                                                        \
        for (int i = 0; i < 4; ++i) {                                            \
            int s = cbase + i;               /* step computes alpha at t=s+1 */  \
            if (s >= t_lim) break;                                               \
            float fm = am + r_[i];                                               \
            float fs = as;                                                       \
            SCAN_STAGE(0x111, 0xf)                                               \
            SCAN_STAGE(0x112, 0xf)                                               \
            SCAN_STAGE(0x114, 0xf)                                               \
            SCAN_STAGE(0x118, 0xf)                                               \
            SCAN_STAGE(0x142, 0xa)                                               \
            SCAN_STAGE(0x143, 0xc)                                               \
            float f64m = a64m + z_[i];                                           \
            float f64s = a64s;                                                   \
            {   float M  = fmaxf(f64m, fm);                                      \
                float ea = vexp2(f64m - M);                                      \
                float eb = vexp2(fm - M);                                        \
                f64s = f64s * ea + fs * eb;                                      \
                f64m = M; }                                                      \
            if (s == t_sel) {                                                    \
                if (l == u_idx) { gm = fm; gs = fs; }                            \
                if (u_idx == 64 && l == 63) { gm = f64m; gs = f64s; }            \
            }                                                                    \
            am = fm; as = fs; a64m = f64m; a64s = f64s;                          \
        }                                                                        \
        { int e1; as = frexpf(as, &e1); am += (float)e1;                         \
          int e2; a64s = frexpf(a64s, &e2); a64m += (float)e2; }                 \
    } while (0)

    LOADG(rA, zA, 0);
    LOADG(rB, zB, 1);
    LOADG(rC, zC, 2);

    for (int cc = 0; cc < 21; ++cc) {
        if (12 * cc >= t_lim) break;
        STEP4(rA, zA, 3 * cc + 0);  LOADG(rA, zA, 3 * cc + 3);
        STEP4(rB, zB, 3 * cc + 1);  LOADG(rB, zB, 3 * cc + 4);
        STEP4(rC, zC, 3 * cc + 2);  LOADG(rC, zC, 3 * cc + 5);
    }
    STEP4(rA, zA, 63);

    int writer_lane = (u_idx < 64) ? u_idx : 63;
    if (l == writer_lane) {
        float g = (gm + vlog2(gs)) * LN2;
        size_t idx = ((size_t)b * 256 + t_idx) * U1 + u_idx;
        float a  = cum[idx] + g;
        float fb = blank[idx];
        atomicAdd(out, -0.125f * (a + fb));
    }
#undef LOADG
#undef SCAN_STAGE
#undef STEP4
}

extern "C" void kernel_launch(void* const* d_in, const int* in_sizes, int n_in,
                              void* d_out, int out_size, void* d_ws, size_t ws_size,
                              hipStream_t stream) {
    const float* logits  = (const float*)d_in[0];
    const int*   targets = (const int*)d_in[1];
    const int*   loglen  = (const int*)d_in[2];
    const int*   tgtlen  = (const int*)d_in[3];

    float* ws    = (float*)d_ws;
    float* blank = ws;                         // B*T*(U+1) = 133120
    float* emit  = blank + BB * TT * U1;       // B*T*U     = 131072
    float* cum   = emit  + BB * TT * UU;       // B*T*(U+1) = 133120
    float* Dg    = cum   + BB * TT * U1;       // 8*64*64*4 = 131072
    float* z64   = Dg    + BB * 64 * 64 * 4;   // B*256     = 2048

    const int nrows = BB * TT * U1;
    k_logsm<<<nrows / 4, 256, 0, stream>>>(logits, targets, loglen, tgtlen, blank, emit);
    k_prep<<<(BB * TT) / 4, 256, 0, stream>>>(emit, blank, loglen, cum, Dg, z64, (float*)d_out);
    k_scan<<<BB, 64, 0, stream>>>(Dg, z64, cum, blank, loglen, tgtlen, (float*)d_out);
}

// Round 8
// 84.235 us; speedup vs baseline: 2.2373x; 1.0138x over previous
//
#include <hip/hip_runtime.h>

#define BB 8
#define TT 256
#define UU 64
#define VV 512
#define U1 (UU + 1)

#define LOG2E 1.4426950408889634f
#define LN2   0.6931471805599453f
#define NEG_INF (-__builtin_inff())

typedef float floatx4 __attribute__((ext_vector_type(4)));

__device__ __forceinline__ float vexp2(float x) {
    float r; asm("v_exp_f32 %0, %1" : "=v"(r) : "v"(x)); return r;
}
__device__ __forceinline__ float vlog2(float x) {
    float r; asm("v_log_f32 %0, %1" : "=v"(r) : "v"(x)); return r;
}
// -|x| via sign-bit set (1 v_or_b32)
__device__ __forceinline__ float negabs(float x) {
    return __int_as_float(__float_as_int(x) | 0x80000000u);
}
__device__ __forceinline__ float rdlane63(float x) {
    return __int_as_float(__builtin_amdgcn_readlane(__float_as_int(x), 63));
}

template<int CTRL, int RMASK>
__device__ __forceinline__ float dpp_mov(float v, float oldv) {
    int r = __builtin_amdgcn_update_dpp(__float_as_int(oldv), __float_as_int(v),
                                        CTRL, RMASK, 0xf, false);
    return __int_as_float(r);
}

// wave64 inclusive add-scan via DPP (identity = 0); strictly low-lane -> high-lane.
__device__ __forceinline__ float wave_addscan(float v) {
    v += dpp_mov<0x111, 0xf>(v, 0.f);
    v += dpp_mov<0x112, 0xf>(v, 0.f);
    v += dpp_mov<0x114, 0xf>(v, 0.f);
    v += dpp_mov<0x118, 0xf>(v, 0.f);
    v += dpp_mov<0x142, 0xa>(v, 0.f);
    v += dpp_mov<0x143, 0xc>(v, 0.f);
    return v;
}
// wave64 inclusive max-scan (identity = -inf); lane 63 = global max.
__device__ __forceinline__ float wave_maxscan(float v) {
    v = fmaxf(v, dpp_mov<0x111, 0xf>(v, NEG_INF));
    v = fmaxf(v, dpp_mov<0x112, 0xf>(v, NEG_INF));
    v = fmaxf(v, dpp_mov<0x114, 0xf>(v, NEG_INF));
    v = fmaxf(v, dpp_mov<0x118, 0xf>(v, NEG_INF));
    v = fmaxf(v, dpp_mov<0x142, 0xa>(v, NEG_INF));
    v = fmaxf(v, dpp_mov<0x143, 0xc>(v, NEG_INF));
    return v;
}

// One alpha-recursion step. (m,s) pairs; exps hoisted off the fs chain; 1 exp/logadd.
__device__ __forceinline__ void scan_step(float r, float z, float& am, float& as,
                                          float& a64m, float& a64s) {
    // max chain (critical path): 6 x (dpp + fmax)
    float f0 = am + r;
    float p1 = dpp_mov<0x111, 0xf>(f0, NEG_INF); float m1 = fmaxf(f0, p1);
    float p2 = dpp_mov<0x112, 0xf>(m1, NEG_INF); float m2 = fmaxf(m1, p2);
    float p3 = dpp_mov<0x114, 0xf>(m2, NEG_INF); float m3 = fmaxf(m2, p3);
    float p4 = dpp_mov<0x118, 0xf>(m3, NEG_INF); float m4 = fmaxf(m3, p4);
    float p5 = dpp_mov<0x142, 0xa>(m4, NEG_INF); float m5 = fmaxf(m4, p5);
    float p6 = dpp_mov<0x143, 0xc>(m5, NEG_INF); float m6 = fmaxf(m5, p6);
    // all exps derive from the max chain only -> issue pipelined, off the fs chain
    float e1 = vexp2(negabs(f0 - p1));
    float e2 = vexp2(negabs(m1 - p2));
    float e3 = vexp2(negabs(m2 - p3));
    float e4 = vexp2(negabs(m3 - p4));
    float e5 = vexp2(negabs(m4 - p5));
    float e6 = vexp2(negabs(m5 - p6));
    bool c1 = f0 >= p1, c2 = m1 >= p2, c3 = m2 >= p3,
         c4 = m3 >= p4, c5 = m4 >= p5, c6 = m5 >= p6;
    // fs chain: 6 x (dpp + 2 cndmask + fma), no trans ops
    float s_ = as;
    { float ps = dpp_mov<0x111, 0xf>(s_, 0.f); float bg = c1 ? s_ : ps, sm = c1 ? ps : s_; s_ = fmaf(sm, e1, bg); }
    { float ps = dpp_mov<0x112, 0xf>(s_, 0.f); float bg = c2 ? s_ : ps, sm = c2 ? ps : s_; s_ = fmaf(sm, e2, bg); }
    { float ps = dpp_mov<0x114, 0xf>(s_, 0.f); float bg = c3 ? s_ : ps, sm = c3 ? ps : s_; s_ = fmaf(sm, e3, bg); }
    { float ps = dpp_mov<0x118, 0xf>(s_, 0.f); float bg = c4 ? s_ : ps, sm = c4 ? ps : s_; s_ = fmaf(sm, e4, bg); }
    { float ps = dpp_mov<0x142, 0xa>(s_, 0.f); float bg = c5 ? s_ : ps, sm = c5 ? ps : s_; s_ = fmaf(sm, e5, bg); }
    { float ps = dpp_mov<0x143, 0xc>(s_, 0.f); float bg = c6 ? s_ : ps, sm = c6 ? ps : s_; s_ = fmaf(sm, e6, bg); }
    // u=64 side-chain (valid at lane 63), 1 exp
    float f64 = a64m + z;
    bool  cc  = f64 >= m6;
    float ee  = vexp2(negabs(f64 - m6));
    float bg = cc ? a64s : s_, sm = cc ? s_ : a64s;
    a64s = fmaf(sm, ee, bg);
    a64m = cc ? f64 : m6;
    am = m6; as = s_;
}

// Kernel 1: per-row log-softmax; extract blank lp and target (emit) lp.
// CULLED: rows with t >= loglen[b] or u > tgtlen[b] are dead.
__global__ __launch_bounds__(256) void k_logsm(const float* __restrict__ logits,
                                               const int* __restrict__ targets,
                                               const int* __restrict__ loglen,
                                               const int* __restrict__ tgtlen,
                                               float* __restrict__ blank,
                                               float* __restrict__ emit) {
    int wave = (int)((blockIdx.x * blockDim.x + threadIdx.x) >> 6);
    int lane = threadIdx.x & 63;
    const int nrows = BB * TT * U1;
    if (wave >= nrows) return;
    int u  = wave % U1;
    int bt = wave / U1;
    int b  = bt / TT;
    int t  = bt - b * TT;
    if (t >= loglen[b] || u > tgtlen[b]) return;   // dead row

    const float* row = logits + (size_t)wave * VV;
    floatx4 v0 = __builtin_nontemporal_load((const floatx4*)(row + lane * 4));
    floatx4 v1 = __builtin_nontemporal_load((const floatx4*)(row + 256 + lane * 4));
    float m8 = fmaxf(fmaxf(fmaxf(v0.x, v0.y), fmaxf(v0.z, v0.w)),
                     fmaxf(fmaxf(v1.x, v1.y), fmaxf(v1.z, v1.w)));
    float M = rdlane63(wave_maxscan(m8));          // uniform global max, VALU-only
    float s8 = __expf(v0.x - M) + __expf(v0.y - M) + __expf(v0.z - M) + __expf(v0.w - M)
             + __expf(v1.x - M) + __expf(v1.y - M) + __expf(v1.z - M) + __expf(v1.w - M);
    float S = rdlane63(wave_addscan(s8));
    float lse = M + __logf(S);

    if (lane == 0) blank[wave] = v0.x - lse;
    if (u < UU) {
        int tgt = targets[b * UU + u];             // in [1, V)
        int owner = (tgt & 255) >> 2;
        if (lane == owner) {
            int slot = tgt & 3;
            float x0 = (tgt < 256) ? v0.x : v1.x;
            float x1 = (tgt < 256) ? v0.y : v1.y;
            float x2 = (tgt < 256) ? v0.z : v1.z;
            float x3 = (tgt < 256) ? v0.w : v1.w;
            float val = (slot == 0) ? x0 : (slot == 1) ? x1 : (slot == 2) ? x2 : x3;
            emit[bt * UU + u] = val - lse;
        }
    }
}

// Kernel 2: build cum (exclusive, nat log) and D/z64 (log2 domain) for the scan.
__global__ __launch_bounds__(256) void k_prep(const float* __restrict__ emit,
                                              const float* __restrict__ blank,
                                              const int* __restrict__ loglen,
                                              float* __restrict__ cum,
                                              float* __restrict__ Dg,
                                              float* __restrict__ z64,
                                              float* __restrict__ out0) {
    int wave = (int)((blockIdx.x * blockDim.x + threadIdx.x) >> 6);
    int l = threadIdx.x & 63;
    if (wave >= BB * TT) return;
    if (wave == 0 && l == 0) out0[0] = 0.f;   // zero output for k_scan's atomicAdd
    int b = wave >> 8, t = wave & 255;
    if (t >= loglen[b]) return;               // scan never reads past t_idx
    float e = emit[wave * UU + l];
    float incl = wave_addscan(e);
    float excl = incl - e;                    // exact 0 at lane 0
    cum[wave * U1 + l] = excl;
    float inclT63 = rdlane63(incl);
    if (l == 63) cum[wave * U1 + 64] = incl;
    if (t >= 1) {
        float eP = emit[(wave - 1) * UU + l];
        float inclP = wave_addscan(eP);
        float exclP = inclP - eP;
        float bl = blank[(size_t)(wave - 1) * U1 + l];
        int s = t - 1;
        Dg[((b * 64 + (s >> 2)) * 64 + l) * 4 + (s & 3)] = (bl + exclP - excl) * LOG2E;
        float inclP63 = rdlane63(inclP);
        if (l == 0)
            z64[wave - 1] = (blank[(size_t)(wave - 1) * U1 + 64] + inclP63 - inclT63) * LOG2E;
    }
}

// Kernel 3: per-batch alpha recursion; (m,s) pairs, exps hoisted, t_lim-culled.
__global__ __launch_bounds__(64) void k_scan(const float* __restrict__ Dg,
                                             const float* __restrict__ z64,
                                             const float* __restrict__ cum,
                                             const float* __restrict__ blank,
                                             const int* __restrict__ loglen,
                                             const int* __restrict__ tgtlen,
                                             float* __restrict__ out) {
    int b = blockIdx.x;
    int l = threadIdx.x;                  // owns u = l (0..63); u=64 side-chain in lane 63
    int t_idx = loglen[b] - 1;
    int u_idx = tgtlen[b];
    int t_sel = t_idx - 1;
    int t_lim = t_idx;                    // execute steps s = 0 .. t_lim-1
    const float* Db = Dg + (size_t)b * 64 * 64 * 4;
    const float* zb = z64 + b * 256;

    float am = 0.f, as = 1.f;             // g pair, g = am + log2(as)
    float a64m = 0.f, a64s = 1.f;
    float gm = 0.f, gs = 1.f;

    float rA[4], zA[4], rB[4], zB[4], rC[4], zC[4];

#define LOADG(r_, z_, c_) do { int c__ = (c_);                                   \
        if (c__ < 64 && 4 * c__ < t_lim) {                                       \
            *(float4*)(r_) = *(const float4*)(Db + (c__ * 64 + l) * 4);          \
            *(float4*)(z_) = *(const float4*)(zb + 4 * c__);                     \
        } } while (0)

#define STEP4(r_, z_, c_) do { int cbase = 4 * (c_);                             \
        _Pragma("unroll")                                                        \
        for (int i = 0; i < 4; ++i) {                                            \
            int s = cbase + i;                                                   \
            if (s >= t_lim) break;                                               \
            scan_step(r_[i], z_[i], am, as, a64m, a64s);                         \
            if (s == t_sel) {                                                    \
                if (l == u_idx) { gm = am; gs = as; }                            \
                if (u_idx == 64 && l == 63) { gm = a64m; gs = a64s; }            \
            }                                                                    \
        }                                                                        \
        { int e1; as = frexpf(as, &e1); am += (float)e1;                         \
          int e2; a64s = frexpf(a64s, &e2); a64m += (float)e2; }                 \
    } while (0)

    LOADG(rA, zA, 0);
    LOADG(rB, zB, 1);
    LOADG(rC, zC, 2);

    for (int cc = 0; cc < 21; ++cc) {
        if (12 * cc >= t_lim) break;
        STEP4(rA, zA, 3 * cc + 0);  LOADG(rA, zA, 3 * cc + 3);
        STEP4(rB, zB, 3 * cc + 1);  LOADG(rB, zB, 3 * cc + 4);
        STEP4(rC, zC, 3 * cc + 2);  LOADG(rC, zC, 3 * cc + 5);
    }
    STEP4(rA, zA, 63);

    int writer_lane = (u_idx < 64) ? u_idx : 63;
    if (l == writer_lane) {
        float g = (gm + vlog2(gs)) * LN2;
        size_t idx = ((size_t)b * 256 + t_idx) * U1 + u_idx;
        float a  = cum[idx] + g;
        float fb = blank[idx];
        atomicAdd(out, -0.125f * (a + fb));
    }
#undef LOADG
#undef STEP4
}

extern "C" void kernel_launch(void* const* d_in, const int* in_sizes, int n_in,
                              void* d_out, int out_size, void* d_ws, size_t ws_size,
                              hipStream_t stream) {
    const float* logits  = (const float*)d_in[0];
    const int*   targets = (const int*)d_in[1];
    const int*   loglen  = (const int*)d_in[2];
    const int*   tgtlen  = (const int*)d_in[3];

    float* ws    = (float*)d_ws;
    float* blank = ws;                         // B*T*(U+1) = 133120
    float* emit  = blank + BB * TT * U1;       // B*T*U     = 131072
    float* cum   = emit  + BB * TT * UU;       // B*T*(U+1) = 133120
    float* Dg    = cum   + BB * TT * U1;       // 8*64*64*4 = 131072
    float* z64   = Dg    + BB * 64 * 64 * 4;   // B*256     = 2048

    const int nrows = BB * TT * U1;
    k_logsm<<<nrows / 4, 256, 0, stream>>>(logits, targets, loglen, tgtlen, blank, emit);
    k_prep<<<(BB * TT) / 4, 256, 0, stream>>>(emit, blank, loglen, cum, Dg, z64, (float*)d_out);
    k_scan<<<BB, 64, 0, stream>>>(Dg, z64, cum, blank, loglen, tgtlen, (float*)d_out);
}